// Round 14
// baseline (122.477 us; speedup 1.0000x reference)
//
#include <hip/hip_runtime.h>
#include <hip/hip_bf16.h>
#include <math.h>

#define B_ 4
#define S_ 2048
#define H_ 1024
#define KC 128
#define EPSF 1e-8f

typedef __attribute__((ext_vector_type(8))) short bf16x8;
typedef __attribute__((ext_vector_type(4))) float f32x4;

static __device__ inline unsigned short f2b(float f) {
    unsigned u = __float_as_uint(f);
    return (unsigned short)((u + 0x7fffu + ((u >> 16) & 1u)) >> 16);  // RNE
}

static __device__ inline unsigned long long shflx64(unsigned long long v, int m) {
    int lo = __shfl_xor((int)(unsigned)(v & 0xffffffffull), m, 64);
    int hi = __shfl_xor((int)(unsigned)(v >> 32), m, 64);
    return ((unsigned long long)(unsigned)hi << 32) | (unsigned)lo;
}

#define CROSS_STAGE(k, j) do {                                              \
    const int lm = (j) >> 3;                                                \
    const bool upL  = (((lane) * 8) & (k)) == 0;                            \
    const bool lowr = ((lane) & lm) == 0;                                   \
    _Pragma("unroll")                                                       \
    for (int r = 0; r < 8; ++r) {                                           \
        unsigned long long o = shflx64(e[r], lm);                           \
        e[r] = ((upL == lowr) == (e[r] < o)) ? e[r] : o;                    \
    }                                                                       \
} while (0)

#define INTRA_STAGE(j, k) do {                                              \
    _Pragma("unroll")                                                       \
    for (int r = 0; r < 8; ++r) if (!(r & (j))) {                           \
        bool up = ((((lane) * 8 + r) & (k)) == 0);                          \
        unsigned long long a = e[r], b = e[r | (j)];                        \
        if (up ? (a > b) : (a < b)) { e[r] = b; e[r | (j)] = a; }           \
    }                                                                       \
} while (0)

static __device__ inline void wave_sort512(unsigned long long e[8], int lane) {
    INTRA_STAGE(1, 2);
    INTRA_STAGE(2, 4);  INTRA_STAGE(1, 4);
    INTRA_STAGE(4, 8);  INTRA_STAGE(2, 8);  INTRA_STAGE(1, 8);
    CROSS_STAGE(16, 8);
    INTRA_STAGE(4, 16); INTRA_STAGE(2, 16); INTRA_STAGE(1, 16);
    CROSS_STAGE(32, 16); CROSS_STAGE(32, 8);
    INTRA_STAGE(4, 32); INTRA_STAGE(2, 32); INTRA_STAGE(1, 32);
    CROSS_STAGE(64, 32); CROSS_STAGE(64, 16); CROSS_STAGE(64, 8);
    INTRA_STAGE(4, 64); INTRA_STAGE(2, 64); INTRA_STAGE(1, 64);
    CROSS_STAGE(128, 64); CROSS_STAGE(128, 32); CROSS_STAGE(128, 16);
    CROSS_STAGE(128, 8);
    INTRA_STAGE(4, 128); INTRA_STAGE(2, 128); INTRA_STAGE(1, 128);
    CROSS_STAGE(256, 128); CROSS_STAGE(256, 64); CROSS_STAGE(256, 32);
    CROSS_STAGE(256, 16); CROSS_STAGE(256, 8);
    INTRA_STAGE(4, 256); INTRA_STAGE(2, 256); INTRA_STAGE(1, 256);
    CROSS_STAGE(512, 256); CROSS_STAGE(512, 128); CROSS_STAGE(512, 64);
    CROSS_STAGE(512, 32); CROSS_STAGE(512, 16); CROSS_STAGE(512, 8);
    INTRA_STAGE(4, 512); INTRA_STAGE(2, 512); INTRA_STAGE(1, 512);
}

static __device__ inline void topk_block(
    const float* logits, const int* mask, int blk,
    int* key_idx, int* val_idx, float* out_idx_base,
    unsigned long long* cand, int tid)
{
    const int b   = blk >> 1;
    const int cls = (blk & 1) ? 2 : 1;
    const int wv = tid >> 6, lane = tid & 63;
    unsigned long long e[8];
    #pragma unroll
    for (int r = 0; r < 8; ++r) {
        int s = wv * 512 + lane * 8 + r;
        float l0 = logits[(b * S_ + s) * 3 + 0];
        float l1 = logits[(b * S_ + s) * 3 + 1];
        float l2 = logits[(b * S_ + s) * 3 + 2];
        int pred = 0; float bl = l0;
        if (l1 > bl) { bl = l1; pred = 1; }
        if (l2 > bl) { bl = l2; pred = 2; }
        float c = -1.0f;
        if (pred == cls && mask[b * S_ + s] == 1) {
            double m = (double)bl;
            double e0 = exp((double)l0 - m);
            double e1 = exp((double)l1 - m);
            double e2 = exp((double)l2 - m);
            c = (float)(((cls == 1) ? e1 : e2) / (e0 + e1 + e2));
        }
        unsigned int u = __float_as_uint(c);
        unsigned int mono = (u & 0x80000000u) ? ~u : (u | 0x80000000u);
        e[r] = ((unsigned long long)(~mono) << 32) | (unsigned int)s;
    }
    wave_sort512(e, lane);
    if (lane < 16) {
        #pragma unroll
        for (int r = 0; r < 8; ++r) cand[wv * 128 + lane * 8 + r] = e[r];
    }
    __syncthreads();
    if (wv == 0) {
        #pragma unroll
        for (int r = 0; r < 8; ++r) e[r] = cand[lane * 8 + r];
        wave_sort512(e, lane);
        if (lane < 16) {
            int* idx_out = (blk & 1) ? (val_idx + b * KC) : (key_idx + b * KC);
            float* oidx  = out_idx_base + ((blk & 1) ? B_ * KC : 0) + b * KC;
            #pragma unroll
            for (int r = 0; r < 8; ++r) {
                int sel = (int)(e[r] & 0xffffffffu);
                idx_out[lane * 8 + r] = sel;
                oidx[lane * 8 + r] = (float)sel;
            }
        }
    }
}

// ------------------------------------------------------------------
// L1: topk (blocks 3072..3079) + weight transpose/convert (0..3071).
// ------------------------------------------------------------------
__global__ __launch_bounds__(256) void prep_kernel(
    const float* __restrict__ Wk, const float* __restrict__ Wv,
    const float* __restrict__ Wbil, unsigned short* __restrict__ Wt,
    const float* __restrict__ logits, const int* __restrict__ mask,
    int* __restrict__ key_idx, int* __restrict__ val_idx,
    float* __restrict__ out_idx)
{
    __shared__ float tile[32][33];
    __shared__ unsigned long long cand[512];
    const int tid = threadIdx.x;
    if (blockIdx.x < 3072) {
        const int z = blockIdx.x >> 10;
        const int remb = blockIdx.x & 1023;
        const float* Win = (z == 0) ? Wk : (z == 1) ? Wv : Wbil;
        unsigned short* out = Wt + (size_t)z * H_ * H_;
        const int n0 = (remb & 31) * 32, k0 = (remb >> 5) * 32;
        const int r = tid >> 3, c0 = (tid & 7) * 4;
        float4 v = *(const float4*)(Win + (size_t)(k0 + r) * H_ + n0 + c0);
        tile[r][c0 + 0] = v.x; tile[r][c0 + 1] = v.y;
        tile[r][c0 + 2] = v.z; tile[r][c0 + 3] = v.w;
        __syncthreads();
        short4 o;
        o.x = (short)f2b(tile[c0 + 0][r]);
        o.y = (short)f2b(tile[c0 + 1][r]);
        o.z = (short)f2b(tile[c0 + 2][r]);
        o.w = (short)f2b(tile[c0 + 3][r]);
        *(short4*)(out + (size_t)(n0 + r) * H_ + k0 + c0) = o;
        return;
    }
    topk_block(logits, mask, blockIdx.x - 3072, key_idx, val_idx, out_idx,
               cand, tid);
}

// ------------------------------------------------------------------
// L2/L3: MFMA GEMM, 16x16 tile per 1-wave block, 1-D grid with
// XCD-chunked swizzle (n-panel-major within each XCD chunk).
// idx != null: A rows gathered from seq (f32->bf16 in-register).
// ------------------------------------------------------------------
__global__ __launch_bounds__(64) void gemm_mfma_kernel(
    const float* __restrict__ seq,          // [B,S,H] f32 (used when idx)
    const unsigned short* __restrict__ Abf, // [M,H] bf16 (used when !idx)
    const int* __restrict__ idx0,           // key_idx base or nullptr
    const unsigned short* __restrict__ Wt,  // [z][1024][1024] bf16 N-major
    const float* __restrict__ b0, const float* __restrict__ b1,
    unsigned short* __restrict__ Cout)      // [z*512+512][1024] bf16
{
    // XCD-chunked swizzle: consecutive hw blocks (round-robin over 8 XCDs)
    // map to contiguous sw ranges -> each XCD owns 1/8 of n-panels.
    const int NW8 = gridDim.x >> 3;
    int sw = (blockIdx.x & 7) * NW8 + (blockIdx.x >> 3);
    const int z  = sw >> 11;                // 2048 tiles per z-slice
    const int r2 = sw & 2047;
    const int n0 = (r2 >> 5) * 16;          // n-major: 64 n-blocks
    const int m0 = (r2 & 31) * 16;          // 32 m-blocks

    Wt   += (size_t)z * H_ * H_;
    Cout += (size_t)z * 512 * H_;
    const float* bias = z ? b1 : b0;
    const int* idx = idx0 ? (idx0 + z * 512) : nullptr;

    const int l  = threadIdx.x;
    const int r  = l & 15;
    const int kb = (l >> 4) * 8;

    f32x4 acc = {};
    const float* s0 = nullptr;
    const unsigned short* a0 = nullptr;
    if (idx) {
        int gm = m0 + r;
        s0 = seq + ((size_t)(gm >> 7) * S_ + idx[gm]) * H_ + kb;
    } else {
        a0 = Abf + (size_t)(m0 + r) * H_ + kb;
    }
    const unsigned short* w0 = Wt + (size_t)(n0 + r) * H_ + kb;

    #pragma unroll 8
    for (int k0 = 0; k0 < H_; k0 += 32) {
        bf16x8 av, bv;
        if (idx) {
            float4 va = *(const float4*)(s0 + k0);
            float4 vb = *(const float4*)(s0 + k0 + 4);
            av[0] = (short)f2b(va.x); av[1] = (short)f2b(va.y);
            av[2] = (short)f2b(va.z); av[3] = (short)f2b(va.w);
            av[4] = (short)f2b(vb.x); av[5] = (short)f2b(vb.y);
            av[6] = (short)f2b(vb.z); av[7] = (short)f2b(vb.w);
        } else {
            av = *(const bf16x8*)(a0 + k0);
        }
        bv = *(const bf16x8*)(w0 + k0);
        acc = __builtin_amdgcn_mfma_f32_16x16x32_bf16(av, bv, acc, 0, 0, 0);
    }

    const int orow = (l >> 4) * 4, ocol = l & 15;
    const int n = n0 + ocol;
    const float bv_ = bias ? bias[n] : 0.0f;
    #pragma unroll
    for (int g = 0; g < 4; ++g)
        Cout[(size_t)(m0 + orow + g) * H_ + n] = f2b(acc[g] + bv_);
}

// ------------------------------------------------------------------
// L4: biaffine (4-wave K-split MFMA) fused with spatial MLP.
// 256 blocks x 256 thr; block = (b, 16x16 biaffine tile); 1 elem/thread.
// ------------------------------------------------------------------
__global__ __launch_bounds__(256) void biasp_kernel(
    const unsigned short* __restrict__ kbt,
    const unsigned short* __restrict__ vrep,
    const float* __restrict__ bbil, const float* __restrict__ bboxes,
    const int* __restrict__ key_idx, const int* __restrict__ val_idx,
    const float* __restrict__ Ws1, const float* __restrict__ bs1,
    const float* __restrict__ Ws2, const float* __restrict__ bs2,
    const float* __restrict__ Wf1, const float* __restrict__ bf1,
    const float* __restrict__ Wf2, const float* __restrict__ bf2,
    float* __restrict__ out)
{
    __shared__ float part[4][16][16];
    __shared__ float4 sWs1T[128];
    __shared__ float  sbs1[64];
    __shared__ float4 sWs2v[512];
    __shared__ float4 sbs2v[8];
    __shared__ float  sWf1c0[16];
    __shared__ float4 sWf1v[128];
    __shared__ float  sbf1[16];
    __shared__ float  sWf2[16];

    const int tid = threadIdx.x;
    for (int i = tid; i < 128; i += 256) {
        int j = i >> 1, q = i & 1;
        sWs1T[i] = (float4){Ws1[(4*q+0)*64+j], Ws1[(4*q+1)*64+j],
                            Ws1[(4*q+2)*64+j], Ws1[(4*q+3)*64+j]};
    }
    for (int i = tid; i < 64;  i += 256) sbs1[i] = bs1[i];
    for (int i = tid; i < 512; i += 256) sWs2v[i] = ((const float4*)Ws2)[i];
    if (tid < 8)  sbs2v[tid] = ((const float4*)bs2)[tid];
    if (tid < 16) sWf1c0[tid] = Wf1[tid];
    for (int i = tid; i < 128; i += 256) {
        int t = i >> 3, q = i & 7;
        sWf1v[i] = (float4){Wf1[(1+4*q+0)*16+t], Wf1[(1+4*q+1)*16+t],
                            Wf1[(1+4*q+2)*16+t], Wf1[(1+4*q+3)*16+t]};
    }
    if (tid < 16) sbf1[tid] = bf1[tid];
    if (tid < 16) sWf2[tid] = Wf2[tid];

    const int b = blockIdx.x >> 6;
    const int t = blockIdx.x & 63;
    const int m0 = (t >> 3) * 16, n0 = (t & 7) * 16;
    const int lane = tid & 63, wv = tid >> 6;
    const int r = lane & 15, kq = (lane >> 4) * 8;

    f32x4 acc = {};
    const unsigned short* a0 = kbt  + (size_t)(b * KC + m0 + r) * H_ + kq;
    const unsigned short* w0 = vrep + (size_t)(b * KC + n0 + r) * H_ + kq;
    #pragma unroll
    for (int kk = 0; kk < 8; ++kk) {
        int k0 = wv * 256 + kk * 32;
        acc = __builtin_amdgcn_mfma_f32_16x16x32_bf16(
            *(const bf16x8*)(a0 + k0), *(const bf16x8*)(w0 + k0), acc, 0, 0, 0);
    }
    const int orow = (lane >> 4) * 4, ocol = lane & 15;
    #pragma unroll
    for (int g = 0; g < 4; ++g) part[wv][orow + g][ocol] = acc[g];
    __syncthreads();

    const int kl = tid >> 4, vl = tid & 15;
    float c0 = part[0][kl][vl] + part[1][kl][vl]
             + part[2][kl][vl] + part[3][kl][vl] + bbil[0];
    const int kg = m0 + kl, vg = n0 + vl;

    const float* kbx = bboxes + ((size_t)b * S_ + key_idx[b * KC + kg]) * 4;
    const float* vbx = bboxes + ((size_t)b * S_ + val_idx[b * KC + vg]) * 4;
    float k0_ = kbx[0], k1_ = kbx[1], k2_ = kbx[2], k3_ = kbx[3];
    float v0_ = vbx[0], v1_ = vbx[1], v2_ = vbx[2], v3_ = vbx[3];

    float kcx = (k0_ + k2_) * 0.5f, kcy = (k1_ + k3_) * 0.5f;
    float vcx = (v0_ + v2_) * 0.5f, vcy = (v1_ + v3_) * 0.5f;
    float dx = vcx - kcx, dy = vcy - kcy;
    float dist = sqrtf(dx * dx + dy * dy + EPSF);
    float angle = atan2f(dy, dx);
    float kh = k3_ - k1_, vh = v3_ - v1_, kw = k2_ - k0_, vw = v2_ - v0_;
    float h_ov = fmaxf(fminf(k3_, v3_) - fmaxf(k1_, v1_), 0.0f);
    float h_align = h_ov / (fminf(kh, vh) + EPSF);
    float v_ov = fmaxf(fminf(k2_, v2_) - fmaxf(k0_, v0_), 0.0f);
    float v_align = v_ov / (fminf(kw, vw) + EPSF);
    float area_ratio = (vh * vw) / (kh * kw + EPSF);
    float aspect = (vw / (vh + EPSF)) / (kw / (kh + EPSF));

    float4 sfa = {dx, dy, dist, angle};
    float4 sfb = {h_align, v_align, area_ratio, aspect};

    float4 h2v[8];
    #pragma unroll
    for (int q = 0; q < 8; ++q) h2v[q] = sbs2v[q];
    for (int j = 0; j < 64; ++j) {
        float4 w1a = sWs1T[j * 2], w1b = sWs1T[j * 2 + 1];
        float a = sbs1[j]
                + sfa.x * w1a.x + sfa.y * w1a.y + sfa.z * w1a.z + sfa.w * w1a.w
                + sfb.x * w1b.x + sfb.y * w1b.y + sfb.z * w1b.z + sfb.w * w1b.w;
        a = fmaxf(a, 0.0f);
        const float4* w2 = &sWs2v[j * 8];
        #pragma unroll
        for (int q = 0; q < 8; ++q) {
            float4 w = w2[q];
            h2v[q].x += a * w.x; h2v[q].y += a * w.y;
            h2v[q].z += a * w.z; h2v[q].w += a * w.w;
        }
    }
    float score = bf2[0];
    for (int tt = 0; tt < 16; ++tt) {
        float f = sbf1[tt] + c0 * sWf1c0[tt];
        const float4* w = &sWf1v[tt * 8];
        #pragma unroll
        for (int q = 0; q < 8; ++q) {
            float4 ww = w[q];
            f += h2v[q].x * ww.x + h2v[q].y * ww.y
               + h2v[q].z * ww.z + h2v[q].w * ww.w;
        }
        score += fmaxf(f, 0.0f) * sWf2[tt];
    }
    out[((size_t)b * KC + kg) * KC + vg] = score;
}

// ------------------------------------------------------------------
extern "C" void kernel_launch(void* const* d_in, const int* in_sizes, int n_in,
                              void* d_out, int out_size, void* d_ws, size_t ws_size,
                              hipStream_t stream) {
    const float* seq    = (const float*)d_in[0];
    const float* logits = (const float*)d_in[1];
    const float* bboxes = (const float*)d_in[2];
    const int*   mask   = (const int*)d_in[3];
    const float* Wk   = (const float*)d_in[4];
    const float* bk   = (const float*)d_in[5];
    const float* Wv   = (const float*)d_in[6];
    const float* bv   = (const float*)d_in[7];
    const float* Wbil = (const float*)d_in[8];
    const float* bbil = (const float*)d_in[9];
    const float* Ws1  = (const float*)d_in[10];
    const float* bs1  = (const float*)d_in[11];
    const float* Ws2  = (const float*)d_in[12];
    const float* bs2  = (const float*)d_in[13];
    const float* Wf1  = (const float*)d_in[14];
    const float* bf1  = (const float*)d_in[15];
    const float* Wf2  = (const float*)d_in[16];
    const float* bf2  = (const float*)d_in[17];

    float* out = (float*)d_out;
    char* ws = (char*)d_ws;

    // ws: idx @64 | Wt 6MB @8192 | reps 2MB (krep|vrep) | kbt 1MB
    int* key_idx = (int*)(ws + 64);
    int* val_idx = key_idx + B_ * KC;
    unsigned short* Wt   = (unsigned short*)(ws + 8192);
    unsigned short* reps = Wt + (size_t)3 * H_ * H_;
    unsigned short* kbt  = reps + (size_t)1024 * H_;

    // L1: topk + weight transposes
    prep_kernel<<<3080, 256, 0, stream>>>(Wk, Wv, Wbil, Wt,
                                          logits, mask, key_idx, val_idx,
                                          out + B_ * KC * KC);
    // L2: krep (z=0) + vrep (z=1), inline gather, 16x16 tiles, XCD swizzle
    gemm_mfma_kernel<<<4096, 64, 0, stream>>>(
        seq, nullptr, key_idx, Wt, bk, bv, reps);
    // L3: kbt = krep @ WbilT (no gather, no bias)
    gemm_mfma_kernel<<<2048, 64, 0, stream>>>(
        nullptr, reps, nullptr, Wt + (size_t)2 * H_ * H_,
        nullptr, nullptr, kbt);
    // L4: biaffine + spatial MLP
    biasp_kernel<<<256, 256, 0, stream>>>(kbt, reps + (size_t)512 * H_,
                                          bbil, bboxes, key_idx, val_idx,
                                          Ws1, bs1, Ws2, bs2,
                                          Wf1, bf1, Wf2, bf2, out);
}

// Round 15
// 95.883 us; speedup vs baseline: 1.2774x; 1.2774x over previous
//
#include <hip/hip_runtime.h>
#include <hip/hip_bf16.h>
#include <math.h>

#define B_ 4
#define S_ 2048
#define H_ 1024
#define KC 128
#define EPSF 1e-8f

typedef __attribute__((ext_vector_type(8))) short bf16x8;
typedef __attribute__((ext_vector_type(4))) float f32x4;

static __device__ inline unsigned short f2b(float f) {
    unsigned u = __float_as_uint(f);
    return (unsigned short)((u + 0x7fffu + ((u >> 16) & 1u)) >> 16);  // RNE
}

static __device__ inline unsigned long long shflx64(unsigned long long v, int m) {
    int lo = __shfl_xor((int)(unsigned)(v & 0xffffffffull), m, 64);
    int hi = __shfl_xor((int)(unsigned)(v >> 32), m, 64);
    return ((unsigned long long)(unsigned)hi << 32) | (unsigned)lo;
}

#define CROSS_STAGE(k, j) do {                                              \
    const int lm = (j) >> 3;                                                \
    const bool upL  = (((lane) * 8) & (k)) == 0;                            \
    const bool lowr = ((lane) & lm) == 0;                                   \
    _Pragma("unroll")                                                       \
    for (int r = 0; r < 8; ++r) {                                           \
        unsigned long long o = shflx64(e[r], lm);                           \
        e[r] = ((upL == lowr) == (e[r] < o)) ? e[r] : o;                    \
    }                                                                       \
} while (0)

#define INTRA_STAGE(j, k) do {                                              \
    _Pragma("unroll")                                                       \
    for (int r = 0; r < 8; ++r) if (!(r & (j))) {                           \
        bool up = ((((lane) * 8 + r) & (k)) == 0);                          \
        unsigned long long a = e[r], b = e[r | (j)];                        \
        if (up ? (a > b) : (a < b)) { e[r] = b; e[r | (j)] = a; }           \
    }                                                                       \
} while (0)

static __device__ inline void wave_sort512(unsigned long long e[8], int lane) {
    INTRA_STAGE(1, 2);
    INTRA_STAGE(2, 4);  INTRA_STAGE(1, 4);
    INTRA_STAGE(4, 8);  INTRA_STAGE(2, 8);  INTRA_STAGE(1, 8);
    CROSS_STAGE(16, 8);
    INTRA_STAGE(4, 16); INTRA_STAGE(2, 16); INTRA_STAGE(1, 16);
    CROSS_STAGE(32, 16); CROSS_STAGE(32, 8);
    INTRA_STAGE(4, 32); INTRA_STAGE(2, 32); INTRA_STAGE(1, 32);
    CROSS_STAGE(64, 32); CROSS_STAGE(64, 16); CROSS_STAGE(64, 8);
    INTRA_STAGE(4, 64); INTRA_STAGE(2, 64); INTRA_STAGE(1, 64);
    CROSS_STAGE(128, 64); CROSS_STAGE(128, 32); CROSS_STAGE(128, 16);
    CROSS_STAGE(128, 8);
    INTRA_STAGE(4, 128); INTRA_STAGE(2, 128); INTRA_STAGE(1, 128);
    CROSS_STAGE(256, 128); CROSS_STAGE(256, 64); CROSS_STAGE(256, 32);
    CROSS_STAGE(256, 16); CROSS_STAGE(256, 8);
    INTRA_STAGE(4, 256); INTRA_STAGE(2, 256); INTRA_STAGE(1, 256);
    CROSS_STAGE(512, 256); CROSS_STAGE(512, 128); CROSS_STAGE(512, 64);
    CROSS_STAGE(512, 32); CROSS_STAGE(512, 16); CROSS_STAGE(512, 8);
    INTRA_STAGE(4, 512); INTRA_STAGE(2, 512); INTRA_STAGE(1, 512);
}

static __device__ inline void topk_block(
    const float* logits, const int* mask, int blk,
    int* key_idx, int* val_idx, float* out_idx_base,
    unsigned long long* cand, int tid)
{
    const int b   = blk >> 1;
    const int cls = (blk & 1) ? 2 : 1;
    const int wv = tid >> 6, lane = tid & 63;
    unsigned long long e[8];
    #pragma unroll
    for (int r = 0; r < 8; ++r) {
        int s = wv * 512 + lane * 8 + r;
        float l0 = logits[(b * S_ + s) * 3 + 0];
        float l1 = logits[(b * S_ + s) * 3 + 1];
        float l2 = logits[(b * S_ + s) * 3 + 2];
        int pred = 0; float bl = l0;
        if (l1 > bl) { bl = l1; pred = 1; }
        if (l2 > bl) { bl = l2; pred = 2; }
        float c = -1.0f;
        if (pred == cls && mask[b * S_ + s] == 1) {
            double m = (double)bl;
            double e0 = exp((double)l0 - m);
            double e1 = exp((double)l1 - m);
            double e2 = exp((double)l2 - m);
            c = (float)(((cls == 1) ? e1 : e2) / (e0 + e1 + e2));
        }
        unsigned int u = __float_as_uint(c);
        unsigned int mono = (u & 0x80000000u) ? ~u : (u | 0x80000000u);
        e[r] = ((unsigned long long)(~mono) << 32) | (unsigned int)s;
    }
    wave_sort512(e, lane);
    if (lane < 16) {
        #pragma unroll
        for (int r = 0; r < 8; ++r) cand[wv * 128 + lane * 8 + r] = e[r];
    }
    __syncthreads();
    if (wv == 0) {
        #pragma unroll
        for (int r = 0; r < 8; ++r) e[r] = cand[lane * 8 + r];
        wave_sort512(e, lane);
        if (lane < 16) {
            int* idx_out = (blk & 1) ? (val_idx + b * KC) : (key_idx + b * KC);
            float* oidx  = out_idx_base + ((blk & 1) ? B_ * KC : 0) + b * KC;
            #pragma unroll
            for (int r = 0; r < 8; ++r) {
                int sel = (int)(e[r] & 0xffffffffu);
                idx_out[lane * 8 + r] = sel;
                oidx[lane * 8 + r] = (float)sel;
            }
        }
    }
}

// ------------------------------------------------------------------
// L1: topk (blocks 3072..3079) + weight transpose/convert (0..3071).
// ------------------------------------------------------------------
__global__ __launch_bounds__(256) void prep_kernel(
    const float* __restrict__ Wk, const float* __restrict__ Wv,
    const float* __restrict__ Wbil, unsigned short* __restrict__ Wt,
    const float* __restrict__ logits, const int* __restrict__ mask,
    int* __restrict__ key_idx, int* __restrict__ val_idx,
    float* __restrict__ out_idx)
{
    __shared__ float tile[32][33];
    __shared__ unsigned long long cand[512];
    const int tid = threadIdx.x;
    if (blockIdx.x < 3072) {
        const int z = blockIdx.x >> 10;
        const int remb = blockIdx.x & 1023;
        const float* Win = (z == 0) ? Wk : (z == 1) ? Wv : Wbil;
        unsigned short* out = Wt + (size_t)z * H_ * H_;
        const int n0 = (remb & 31) * 32, k0 = (remb >> 5) * 32;
        const int r = tid >> 3, c0 = (tid & 7) * 4;
        float4 v = *(const float4*)(Win + (size_t)(k0 + r) * H_ + n0 + c0);
        tile[r][c0 + 0] = v.x; tile[r][c0 + 1] = v.y;
        tile[r][c0 + 2] = v.z; tile[r][c0 + 3] = v.w;
        __syncthreads();
        short4 o;
        o.x = (short)f2b(tile[c0 + 0][r]);
        o.y = (short)f2b(tile[c0 + 1][r]);
        o.z = (short)f2b(tile[c0 + 2][r]);
        o.w = (short)f2b(tile[c0 + 3][r]);
        *(short4*)(out + (size_t)(n0 + r) * H_ + k0 + c0) = o;
        return;
    }
    topk_block(logits, mask, blockIdx.x - 3072, key_idx, val_idx, out_idx,
               cand, tid);
}

// ------------------------------------------------------------------
// L2/L3: K-split MFMA GEMM. One 32x32 output tile per 256-thread block;
// 4 waves each cover K=256 (8 fully-unrolled iters); LDS reduce.
// idx != null: A rows gathered from seq (f32->bf16 in-register).
// XCD-chunked 1-D swizzle; 512 tiles per z-slice.
// ------------------------------------------------------------------
__global__ __launch_bounds__(256) void gemm_ks_kernel(
    const float* __restrict__ seq,          // [B,S,H] f32 (used when idx)
    const unsigned short* __restrict__ Abf, // [M,H] bf16 (used when !idx)
    const int* __restrict__ idx0,           // key_idx base or nullptr
    const unsigned short* __restrict__ Wt,  // [z][1024][1024] bf16 N-major
    const float* __restrict__ b0, const float* __restrict__ b1,
    unsigned short* __restrict__ Cout)      // [z*512+512][1024] bf16
{
    __shared__ float part[4][32][33];

    const int NW8 = gridDim.x >> 3;
    int sw = ((int)blockIdx.x & 7) * NW8 + ((int)blockIdx.x >> 3);
    const int z  = sw >> 9;                 // 512 tiles per z-slice
    const int r2 = sw & 511;
    const int n0 = (r2 >> 4) * 32;          // n-major: 32 n-blocks
    const int m0 = (r2 & 15) * 32;          // 16 m-blocks

    Wt   += (size_t)z * H_ * H_;
    Cout += (size_t)z * 512 * H_;
    const float* bias = z ? b1 : b0;
    const int* idx = idx0 ? (idx0 + z * 512) : nullptr;

    const int tid  = threadIdx.x;
    const int lane = tid & 63, wv = tid >> 6;
    const int r = lane & 15, kb = (lane >> 4) * 8;
    const int kbase = wv * 256 + kb;

    f32x4 acc[2][2] = {};
    const float* s0 = nullptr; const float* s1 = nullptr;
    const unsigned short* a0 = nullptr; const unsigned short* a1 = nullptr;
    if (idx) {
        int gm0 = m0 + r, gm1 = m0 + 16 + r;
        s0 = seq + ((size_t)(gm0 >> 7) * S_ + idx[gm0]) * H_ + kbase;
        s1 = seq + ((size_t)(gm1 >> 7) * S_ + idx[gm1]) * H_ + kbase;
    } else {
        a0 = Abf + (size_t)(m0 + r) * H_ + kbase;
        a1 = a0 + 16 * H_;
    }
    const unsigned short* w0 = Wt + (size_t)(n0 + r) * H_ + kbase;
    const unsigned short* w1 = w0 + 16 * H_;

    #pragma unroll
    for (int k0 = 0; k0 < 256; k0 += 32) {
        bf16x8 av[2], bv[2];
        if (idx) {
            #pragma unroll
            for (int i = 0; i < 2; ++i) {
                const float* sp = i ? s1 : s0;
                float4 va = *(const float4*)(sp + k0);
                float4 vb = *(const float4*)(sp + k0 + 4);
                av[i][0] = (short)f2b(va.x); av[i][1] = (short)f2b(va.y);
                av[i][2] = (short)f2b(va.z); av[i][3] = (short)f2b(va.w);
                av[i][4] = (short)f2b(vb.x); av[i][5] = (short)f2b(vb.y);
                av[i][6] = (short)f2b(vb.z); av[i][7] = (short)f2b(vb.w);
            }
        } else {
            av[0] = *(const bf16x8*)(a0 + k0);
            av[1] = *(const bf16x8*)(a1 + k0);
        }
        bv[0] = *(const bf16x8*)(w0 + k0);
        bv[1] = *(const bf16x8*)(w1 + k0);
        #pragma unroll
        for (int i = 0; i < 2; ++i)
            #pragma unroll
            for (int j = 0; j < 2; ++j)
                acc[i][j] = __builtin_amdgcn_mfma_f32_16x16x32_bf16(
                    av[i], bv[j], acc[i][j], 0, 0, 0);
    }

    const int orow = (lane >> 4) * 4, ocol = lane & 15;
    #pragma unroll
    for (int i = 0; i < 2; ++i)
        #pragma unroll
        for (int j = 0; j < 2; ++j)
            #pragma unroll
            for (int g = 0; g < 4; ++g)
                part[wv][i * 16 + orow + g][j * 16 + ocol] = acc[i][j][g];
    __syncthreads();

    // reduce 4 partials; thread -> (row mr, 4 consecutive n), short4 store
    const int mr = tid >> 3, nq = (tid & 7) * 4;
    short4 o;
    #pragma unroll
    for (int q = 0; q < 4; ++q) {
        float c = part[0][mr][nq + q] + part[1][mr][nq + q]
                + part[2][mr][nq + q] + part[3][mr][nq + q];
        if (bias) c += bias[n0 + nq + q];
        ((short*)&o)[q] = (short)f2b(c);
    }
    *(short4*)(Cout + (size_t)(m0 + mr) * H_ + n0 + nq) = o;
}

// ------------------------------------------------------------------
// L4: biaffine (4-wave K-split MFMA) fused with spatial MLP.
// 256 blocks x 256 thr; block = (b, 16x16 biaffine tile); 1 elem/thread.
// ------------------------------------------------------------------
__global__ __launch_bounds__(256) void biasp_kernel(
    const unsigned short* __restrict__ kbt,
    const unsigned short* __restrict__ vrep,
    const float* __restrict__ bbil, const float* __restrict__ bboxes,
    const int* __restrict__ key_idx, const int* __restrict__ val_idx,
    const float* __restrict__ Ws1, const float* __restrict__ bs1,
    const float* __restrict__ Ws2, const float* __restrict__ bs2,
    const float* __restrict__ Wf1, const float* __restrict__ bf1,
    const float* __restrict__ Wf2, const float* __restrict__ bf2,
    float* __restrict__ out)
{
    __shared__ float part[4][16][16];
    __shared__ float4 sWs1T[128];
    __shared__ float  sbs1[64];
    __shared__ float4 sWs2v[512];
    __shared__ float4 sbs2v[8];
    __shared__ float  sWf1c0[16];
    __shared__ float4 sWf1v[128];
    __shared__ float  sbf1[16];
    __shared__ float  sWf2[16];

    const int tid = threadIdx.x;
    for (int i = tid; i < 128; i += 256) {
        int j = i >> 1, q = i & 1;
        sWs1T[i] = (float4){Ws1[(4*q+0)*64+j], Ws1[(4*q+1)*64+j],
                            Ws1[(4*q+2)*64+j], Ws1[(4*q+3)*64+j]};
    }
    for (int i = tid; i < 64;  i += 256) sbs1[i] = bs1[i];
    for (int i = tid; i < 512; i += 256) sWs2v[i] = ((const float4*)Ws2)[i];
    if (tid < 8)  sbs2v[tid] = ((const float4*)bs2)[tid];
    if (tid < 16) sWf1c0[tid] = Wf1[tid];
    for (int i = tid; i < 128; i += 256) {
        int t = i >> 3, q = i & 7;
        sWf1v[i] = (float4){Wf1[(1+4*q+0)*16+t], Wf1[(1+4*q+1)*16+t],
                            Wf1[(1+4*q+2)*16+t], Wf1[(1+4*q+3)*16+t]};
    }
    if (tid < 16) sbf1[tid] = bf1[tid];
    if (tid < 16) sWf2[tid] = Wf2[tid];

    const int b = blockIdx.x >> 6;
    const int t = blockIdx.x & 63;
    const int m0 = (t >> 3) * 16, n0 = (t & 7) * 16;
    const int lane = tid & 63, wv = tid >> 6;
    const int r = lane & 15, kq = (lane >> 4) * 8;

    f32x4 acc = {};
    const unsigned short* a0 = kbt  + (size_t)(b * KC + m0 + r) * H_ + kq;
    const unsigned short* w0 = vrep + (size_t)(b * KC + n0 + r) * H_ + kq;
    #pragma unroll
    for (int kk = 0; kk < 8; ++kk) {
        int k0 = wv * 256 + kk * 32;
        acc = __builtin_amdgcn_mfma_f32_16x16x32_bf16(
            *(const bf16x8*)(a0 + k0), *(const bf16x8*)(w0 + k0), acc, 0, 0, 0);
    }
    const int orow = (lane >> 4) * 4, ocol = lane & 15;
    #pragma unroll
    for (int g = 0; g < 4; ++g) part[wv][orow + g][ocol] = acc[g];
    __syncthreads();

    const int kl = tid >> 4, vl = tid & 15;
    float c0 = part[0][kl][vl] + part[1][kl][vl]
             + part[2][kl][vl] + part[3][kl][vl] + bbil[0];
    const int kg = m0 + kl, vg = n0 + vl;

    const float* kbx = bboxes + ((size_t)b * S_ + key_idx[b * KC + kg]) * 4;
    const float* vbx = bboxes + ((size_t)b * S_ + val_idx[b * KC + vg]) * 4;
    float k0_ = kbx[0], k1_ = kbx[1], k2_ = kbx[2], k3_ = kbx[3];
    float v0_ = vbx[0], v1_ = vbx[1], v2_ = vbx[2], v3_ = vbx[3];

    float kcx = (k0_ + k2_) * 0.5f, kcy = (k1_ + k3_) * 0.5f;
    float vcx = (v0_ + v2_) * 0.5f, vcy = (v1_ + v3_) * 0.5f;
    float dx = vcx - kcx, dy = vcy - kcy;
    float dist = sqrtf(dx * dx + dy * dy + EPSF);
    float angle = atan2f(dy, dx);
    float kh = k3_ - k1_, vh = v3_ - v1_, kw = k2_ - k0_, vw = v2_ - v0_;
    float h_ov = fmaxf(fminf(k3_, v3_) - fmaxf(k1_, v1_), 0.0f);
    float h_align = h_ov / (fminf(kh, vh) + EPSF);
    float v_ov = fmaxf(fminf(k2_, v2_) - fmaxf(k0_, v0_), 0.0f);
    float v_align = v_ov / (fminf(kw, vw) + EPSF);
    float area_ratio = (vh * vw) / (kh * kw + EPSF);
    float aspect = (vw / (vh + EPSF)) / (kw / (kh + EPSF));

    float4 sfa = {dx, dy, dist, angle};
    float4 sfb = {h_align, v_align, area_ratio, aspect};

    float4 h2v[8];
    #pragma unroll
    for (int q = 0; q < 8; ++q) h2v[q] = sbs2v[q];
    for (int j = 0; j < 64; ++j) {
        float4 w1a = sWs1T[j * 2], w1b = sWs1T[j * 2 + 1];
        float a = sbs1[j]
                + sfa.x * w1a.x + sfa.y * w1a.y + sfa.z * w1a.z + sfa.w * w1a.w
                + sfb.x * w1b.x + sfb.y * w1b.y + sfb.z * w1b.z + sfb.w * w1b.w;
        a = fmaxf(a, 0.0f);
        const float4* w2 = &sWs2v[j * 8];
        #pragma unroll
        for (int q = 0; q < 8; ++q) {
            float4 w = w2[q];
            h2v[q].x += a * w.x; h2v[q].y += a * w.y;
            h2v[q].z += a * w.z; h2v[q].w += a * w.w;
        }
    }
    float score = bf2[0];
    for (int tt = 0; tt < 16; ++tt) {
        float f = sbf1[tt] + c0 * sWf1c0[tt];
        const float4* w = &sWf1v[tt * 8];
        #pragma unroll
        for (int q = 0; q < 8; ++q) {
            float4 ww = w[q];
            f += h2v[q].x * ww.x + h2v[q].y * ww.y
               + h2v[q].z * ww.z + h2v[q].w * ww.w;
        }
        score += fmaxf(f, 0.0f) * sWf2[tt];
    }
    out[((size_t)b * KC + kg) * KC + vg] = score;
}

// ------------------------------------------------------------------
extern "C" void kernel_launch(void* const* d_in, const int* in_sizes, int n_in,
                              void* d_out, int out_size, void* d_ws, size_t ws_size,
                              hipStream_t stream) {
    const float* seq    = (const float*)d_in[0];
    const float* logits = (const float*)d_in[1];
    const float* bboxes = (const float*)d_in[2];
    const int*   mask   = (const int*)d_in[3];
    const float* Wk   = (const float*)d_in[4];
    const float* bk   = (const float*)d_in[5];
    const float* Wv   = (const float*)d_in[6];
    const float* bv   = (const float*)d_in[7];
    const float* Wbil = (const float*)d_in[8];
    const float* bbil = (const float*)d_in[9];
    const float* Ws1  = (const float*)d_in[10];
    const float* bs1  = (const float*)d_in[11];
    const float* Ws2  = (const float*)d_in[12];
    const float* bs2  = (const float*)d_in[13];
    const float* Wf1  = (const float*)d_in[14];
    const float* bf1  = (const float*)d_in[15];
    const float* Wf2  = (const float*)d_in[16];
    const float* bf2  = (const float*)d_in[17];

    float* out = (float*)d_out;
    char* ws = (char*)d_ws;

    // ws: idx @64 | Wt 6MB @8192 | reps 2MB (krep|vrep) | kbt 1MB
    int* key_idx = (int*)(ws + 64);
    int* val_idx = key_idx + B_ * KC;
    unsigned short* Wt   = (unsigned short*)(ws + 8192);
    unsigned short* reps = Wt + (size_t)3 * H_ * H_;
    unsigned short* kbt  = reps + (size_t)1024 * H_;

    // L1: topk + weight transposes
    prep_kernel<<<3080, 256, 0, stream>>>(Wk, Wv, Wbil, Wt,
                                          logits, mask, key_idx, val_idx,
                                          out + B_ * KC * KC);
    // L2: krep (z=0) + vrep (z=1), inline gather, K-split 32x32 tiles
    gemm_ks_kernel<<<1024, 256, 0, stream>>>(
        seq, nullptr, key_idx, Wt, bk, bv, reps);
    // L3: kbt = krep @ WbilT (no gather, no bias)
    gemm_ks_kernel<<<512, 256, 0, stream>>>(
        nullptr, reps, nullptr, Wt + (size_t)2 * H_ * H_,
        nullptr, nullptr, kbt);
    // L4: biaffine + spatial MLP
    biasp_kernel<<<256, 256, 0, stream>>>(kbt, reps + (size_t)512 * H_,
                                          bbil, bboxes, key_idx, val_idx,
                                          Ws1, bs1, Ws2, bs2,
                                          Wf1, bf1, Wf2, bf2, out);
}

// Round 16
// 73.642 us; speedup vs baseline: 1.6632x; 1.3020x over previous
//
#include <hip/hip_runtime.h>
#include <hip/hip_bf16.h>
#include <math.h>

#define B_ 4
#define S_ 2048
#define H_ 1024
#define KC 128
#define EPSF 1e-8f

typedef __attribute__((ext_vector_type(8))) short bf16x8;
typedef __attribute__((ext_vector_type(4))) float f32x4;

static __device__ inline unsigned short f2b(float f) {
    unsigned u = __float_as_uint(f);
    return (unsigned short)((u + 0x7fffu + ((u >> 16) & 1u)) >> 16);  // RNE
}

static __device__ inline unsigned long long shflx64(unsigned long long v, int m) {
    int lo = __shfl_xor((int)(unsigned)(v & 0xffffffffull), m, 64);
    int hi = __shfl_xor((int)(unsigned)(v >> 32), m, 64);
    return ((unsigned long long)(unsigned)hi << 32) | (unsigned)lo;
}

#define CROSS_STAGE(k, j) do {                                              \
    const int lm = (j) >> 3;                                                \
    const bool upL  = (((lane) * 8) & (k)) == 0;                            \
    const bool lowr = ((lane) & lm) == 0;                                   \
    _Pragma("unroll")                                                       \
    for (int r = 0; r < 8; ++r) {                                           \
        unsigned long long o = shflx64(e[r], lm);                           \
        e[r] = ((upL == lowr) == (e[r] < o)) ? e[r] : o;                    \
    }                                                                       \
} while (0)

#define INTRA_STAGE(j, k) do {                                              \
    _Pragma("unroll")                                                       \
    for (int r = 0; r < 8; ++r) if (!(r & (j))) {                           \
        bool up = ((((lane) * 8 + r) & (k)) == 0);                          \
        unsigned long long a = e[r], b = e[r | (j)];                        \
        if (up ? (a > b) : (a < b)) { e[r] = b; e[r | (j)] = a; }           \
    }                                                                       \
} while (0)

static __device__ inline void wave_sort512(unsigned long long e[8], int lane) {
    INTRA_STAGE(1, 2);
    INTRA_STAGE(2, 4);  INTRA_STAGE(1, 4);
    INTRA_STAGE(4, 8);  INTRA_STAGE(2, 8);  INTRA_STAGE(1, 8);
    CROSS_STAGE(16, 8);
    INTRA_STAGE(4, 16); INTRA_STAGE(2, 16); INTRA_STAGE(1, 16);
    CROSS_STAGE(32, 16); CROSS_STAGE(32, 8);
    INTRA_STAGE(4, 32); INTRA_STAGE(2, 32); INTRA_STAGE(1, 32);
    CROSS_STAGE(64, 32); CROSS_STAGE(64, 16); CROSS_STAGE(64, 8);
    INTRA_STAGE(4, 64); INTRA_STAGE(2, 64); INTRA_STAGE(1, 64);
    CROSS_STAGE(128, 64); CROSS_STAGE(128, 32); CROSS_STAGE(128, 16);
    CROSS_STAGE(128, 8);
    INTRA_STAGE(4, 128); INTRA_STAGE(2, 128); INTRA_STAGE(1, 128);
    CROSS_STAGE(256, 128); CROSS_STAGE(256, 64); CROSS_STAGE(256, 32);
    CROSS_STAGE(256, 16); CROSS_STAGE(256, 8);
    INTRA_STAGE(4, 256); INTRA_STAGE(2, 256); INTRA_STAGE(1, 256);
    CROSS_STAGE(512, 256); CROSS_STAGE(512, 128); CROSS_STAGE(512, 64);
    CROSS_STAGE(512, 32); CROSS_STAGE(512, 16); CROSS_STAGE(512, 8);
    INTRA_STAGE(4, 512); INTRA_STAGE(2, 512); INTRA_STAGE(1, 512);
}

static __device__ inline void topk_block(
    const float* logits, const int* mask, int blk,
    int* key_idx, int* val_idx, float* out_idx_base,
    unsigned long long* cand, int tid)
{
    const int b   = blk >> 1;
    const int cls = (blk & 1) ? 2 : 1;
    const int wv = tid >> 6, lane = tid & 63;
    unsigned long long e[8];
    #pragma unroll
    for (int r = 0; r < 8; ++r) {
        int s = wv * 512 + lane * 8 + r;
        float l0 = logits[(b * S_ + s) * 3 + 0];
        float l1 = logits[(b * S_ + s) * 3 + 1];
        float l2 = logits[(b * S_ + s) * 3 + 2];
        int pred = 0; float bl = l0;
        if (l1 > bl) { bl = l1; pred = 1; }
        if (l2 > bl) { bl = l2; pred = 2; }
        float c = -1.0f;
        if (pred == cls && mask[b * S_ + s] == 1) {
            double m = (double)bl;
            double e0 = exp((double)l0 - m);
            double e1 = exp((double)l1 - m);
            double e2 = exp((double)l2 - m);
            c = (float)(((cls == 1) ? e1 : e2) / (e0 + e1 + e2));
        }
        unsigned int u = __float_as_uint(c);
        unsigned int mono = (u & 0x80000000u) ? ~u : (u | 0x80000000u);
        e[r] = ((unsigned long long)(~mono) << 32) | (unsigned int)s;
    }
    wave_sort512(e, lane);
    if (lane < 16) {
        #pragma unroll
        for (int r = 0; r < 8; ++r) cand[wv * 128 + lane * 8 + r] = e[r];
    }
    __syncthreads();
    if (wv == 0) {
        #pragma unroll
        for (int r = 0; r < 8; ++r) e[r] = cand[lane * 8 + r];
        wave_sort512(e, lane);
        if (lane < 16) {
            int* idx_out = (blk & 1) ? (val_idx + b * KC) : (key_idx + b * KC);
            float* oidx  = out_idx_base + ((blk & 1) ? B_ * KC : 0) + b * KC;
            #pragma unroll
            for (int r = 0; r < 8; ++r) {
                int sel = (int)(e[r] & 0xffffffffu);
                idx_out[lane * 8 + r] = sel;
                oidx[lane * 8 + r] = (float)sel;
            }
        }
    }
}

// ------------------------------------------------------------------
// L1: topk (blocks 3072..3079) + weight transpose/convert (0..3071).
// ------------------------------------------------------------------
__global__ __launch_bounds__(256) void prep_kernel(
    const float* __restrict__ Wk, const float* __restrict__ Wv,
    const float* __restrict__ Wbil, unsigned short* __restrict__ Wt,
    const float* __restrict__ logits, const int* __restrict__ mask,
    int* __restrict__ key_idx, int* __restrict__ val_idx,
    float* __restrict__ out_idx)
{
    __shared__ float tile[32][33];
    __shared__ unsigned long long cand[512];
    const int tid = threadIdx.x;
    if (blockIdx.x < 3072) {
        const int z = blockIdx.x >> 10;
        const int remb = blockIdx.x & 1023;
        const float* Win = (z == 0) ? Wk : (z == 1) ? Wv : Wbil;
        unsigned short* out = Wt + (size_t)z * H_ * H_;
        const int n0 = (remb & 31) * 32, k0 = (remb >> 5) * 32;
        const int r = tid >> 3, c0 = (tid & 7) * 4;
        float4 v = *(const float4*)(Win + (size_t)(k0 + r) * H_ + n0 + c0);
        tile[r][c0 + 0] = v.x; tile[r][c0 + 1] = v.y;
        tile[r][c0 + 2] = v.z; tile[r][c0 + 3] = v.w;
        __syncthreads();
        short4 o;
        o.x = (short)f2b(tile[c0 + 0][r]);
        o.y = (short)f2b(tile[c0 + 1][r]);
        o.z = (short)f2b(tile[c0 + 2][r]);
        o.w = (short)f2b(tile[c0 + 3][r]);
        *(short4*)(out + (size_t)(n0 + r) * H_ + k0 + c0) = o;
        return;
    }
    topk_block(logits, mask, blockIdx.x - 3072, key_idx, val_idx, out_idx,
               cand, tid);
}

// ------------------------------------------------------------------
// L2: gather seq rows by idx, convert to bf16 once.
// ------------------------------------------------------------------
__global__ __launch_bounds__(256) void gatherconv_kernel(
    const float* __restrict__ seq,
    const int* __restrict__ key_idx, const int* __restrict__ val_idx,
    unsigned short* __restrict__ Abf)
{
    const int row = blockIdx.x;
    const int tid = threadIdx.x;
    int b, srow;
    if (row < 512) { b = row >> 7; srow = key_idx[row]; }
    else           { b = (row - 512) >> 7; srow = val_idx[row - 512]; }
    const float* src = seq + ((size_t)b * S_ + srow) * H_ + tid * 4;
    float4 v = *(const float4*)src;
    short4 o;
    o.x = (short)f2b(v.x); o.y = (short)f2b(v.y);
    o.z = (short)f2b(v.z); o.w = (short)f2b(v.w);
    *(short4*)(Abf + (size_t)row * H_ + tid * 4) = o;
}

// ------------------------------------------------------------------
// L3/L4: LDS-staged MFMA GEMM. 32x64 output tile per 256-thr block;
// BK=128; A/B staged to XOR-swizzled LDS with per-wave-contiguous
// global bursts; 4 waves each compute 32m x 16n.
// ------------------------------------------------------------------
__global__ __launch_bounds__(256) void gemm_lds_kernel(
    const unsigned short* __restrict__ Ab,   // [z*512+512][1024] bf16
    const unsigned short* __restrict__ Wt,   // [z][1024][1024] bf16 N-major
    const float* __restrict__ b0, const float* __restrict__ b1,
    unsigned short* __restrict__ Cout)       // [z*512+512][1024] bf16
{
    __shared__ __align__(16) char As[32 * 256];   // 32 rows x 128 bf16, swz
    __shared__ __align__(16) char Bs[64 * 256];   // 64 rows x 128 bf16, swz

    const int NW8 = gridDim.x >> 3;
    int sw = ((int)blockIdx.x & 7) * NW8 + ((int)blockIdx.x >> 3);
    const int z  = sw >> 8;                  // 256 tiles per z-slice
    const int r2 = sw & 255;
    const int n0 = (r2 >> 4) * 64;           // 16 n-tiles (n-major per XCD)
    const int m0 = (r2 & 15) * 32;           // 16 m-tiles

    Ab   += (size_t)z * 512 * H_;
    Cout += (size_t)z * 512 * H_;
    const unsigned short* Wz = Wt + (size_t)z * H_ * H_;
    const float* bias = z ? b1 : b0;

    const int tid  = threadIdx.x;
    const int lane = tid & 63, wv = tid >> 6;
    const int r = lane & 15, kq = (lane >> 4) * 8;

    const int srow = tid >> 3, sch = tid & 7;    // staging: (row, 16B chunk)

    f32x4 acc[2] = {};

    for (int k0 = 0; k0 < H_; k0 += 128) {
        // ---- stage A (32x128) + B (64x128), contiguous per-wave bursts
        {
            bf16x8 va = *(const bf16x8*)(Ab + (size_t)(m0 + srow) * H_
                                         + k0 + sch * 8);
            *(bf16x8*)(As + srow * 256 + ((sch ^ (srow & 7)) << 4)) = va;
            #pragma unroll
            for (int p = 0; p < 2; ++p) {
                int rb = p * 32 + srow;
                bf16x8 vb = *(const bf16x8*)(Wz + (size_t)(n0 + rb) * H_
                                             + k0 + sch * 8);
                *(bf16x8*)(Bs + rb * 256 + ((sch ^ (rb & 7)) << 4)) = vb;
            }
        }
        __syncthreads();
        // ---- compute: 4 kk-steps x (2 m-frags x 1 n-frag)
        #pragma unroll
        for (int kk = 0; kk < 4; ++kk) {
            const int chv = ((kk * 32 + kq) >> 3) ^ (r & 7);
            bf16x8 av0 = *(const bf16x8*)(As + r * 256 + (chv << 4));
            bf16x8 av1 = *(const bf16x8*)(As + (16 + r) * 256 + (chv << 4));
            bf16x8 bv  = *(const bf16x8*)(Bs + (wv * 16 + r) * 256 + (chv << 4));
            acc[0] = __builtin_amdgcn_mfma_f32_16x16x32_bf16(av0, bv, acc[0], 0, 0, 0);
            acc[1] = __builtin_amdgcn_mfma_f32_16x16x32_bf16(av1, bv, acc[1], 0, 0, 0);
        }
        __syncthreads();
    }

    const int orow = (lane >> 4) * 4, ocol = lane & 15;
    const int n = n0 + wv * 16 + ocol;
    const float bv_ = bias ? bias[n] : 0.0f;
    #pragma unroll
    for (int i = 0; i < 2; ++i)
        #pragma unroll
        for (int g = 0; g < 4; ++g)
            Cout[(size_t)(m0 + i * 16 + orow + g) * H_ + n] = f2b(acc[i][g] + bv_);
}

// ------------------------------------------------------------------
// L5: biaffine (8-wave K-split MFMA) fused with spatial MLP.
// 256 blocks x 512 thr; block = (b, 16x16 tile); MLP on tid<256.
// ------------------------------------------------------------------
__global__ __launch_bounds__(512) void biasp_kernel(
    const unsigned short* __restrict__ kbt,
    const unsigned short* __restrict__ vrep,
    const float* __restrict__ bbil, const float* __restrict__ bboxes,
    const int* __restrict__ key_idx, const int* __restrict__ val_idx,
    const float* __restrict__ Ws1, const float* __restrict__ bs1,
    const float* __restrict__ Ws2, const float* __restrict__ bs2,
    const float* __restrict__ Wf1, const float* __restrict__ bf1,
    const float* __restrict__ Wf2, const float* __restrict__ bf2,
    float* __restrict__ out)
{
    __shared__ float part[8][16][16];
    __shared__ float4 sWs1T[128];
    __shared__ float  sbs1[64];
    __shared__ float4 sWs2v[512];
    __shared__ float4 sbs2v[8];
    __shared__ float  sWf1c0[16];
    __shared__ float4 sWf1v[128];
    __shared__ float  sbf1[16];
    __shared__ float  sWf2[16];

    const int tid = threadIdx.x;
    for (int i = tid; i < 128; i += 512) {
        int j = i >> 1, q = i & 1;
        sWs1T[i] = (float4){Ws1[(4*q+0)*64+j], Ws1[(4*q+1)*64+j],
                            Ws1[(4*q+2)*64+j], Ws1[(4*q+3)*64+j]};
    }
    for (int i = tid; i < 64;  i += 512) sbs1[i] = bs1[i];
    if (tid < 512) sWs2v[tid] = ((const float4*)Ws2)[tid];
    if (tid < 8)  sbs2v[tid] = ((const float4*)bs2)[tid];
    if (tid < 16) sWf1c0[tid] = Wf1[tid];
    for (int i = tid; i < 128; i += 512) {
        int t = i >> 3, q = i & 7;
        sWf1v[i] = (float4){Wf1[(1+4*q+0)*16+t], Wf1[(1+4*q+1)*16+t],
                            Wf1[(1+4*q+2)*16+t], Wf1[(1+4*q+3)*16+t]};
    }
    if (tid < 16) sbf1[tid] = bf1[tid];
    if (tid < 16) sWf2[tid] = Wf2[tid];

    const int b = blockIdx.x >> 6;
    const int t = blockIdx.x & 63;
    const int m0 = (t >> 3) * 16, n0 = (t & 7) * 16;
    const int lane = tid & 63, wv = tid >> 6;    // 8 waves
    const int r = lane & 15, kq = (lane >> 4) * 8;

    f32x4 acc = {};
    const unsigned short* a0 = kbt  + (size_t)(b * KC + m0 + r) * H_ + kq;
    const unsigned short* w0 = vrep + (size_t)(b * KC + n0 + r) * H_ + kq;
    #pragma unroll
    for (int kk = 0; kk < 4; ++kk) {
        int k0 = wv * 128 + kk * 32;
        acc = __builtin_amdgcn_mfma_f32_16x16x32_bf16(
            *(const bf16x8*)(a0 + k0), *(const bf16x8*)(w0 + k0), acc, 0, 0, 0);
    }
    const int orow = (lane >> 4) * 4, ocol = lane & 15;
    #pragma unroll
    for (int g = 0; g < 4; ++g) part[wv][orow + g][ocol] = acc[g];
    __syncthreads();

    if (tid >= 256) return;

    const int kl = tid >> 4, vl = tid & 15;
    float c0 = bbil[0];
    #pragma unroll
    for (int w = 0; w < 8; ++w) c0 += part[w][kl][vl];
    const int kg = m0 + kl, vg = n0 + vl;

    const float* kbx = bboxes + ((size_t)b * S_ + key_idx[b * KC + kg]) * 4;
    const float* vbx = bboxes + ((size_t)b * S_ + val_idx[b * KC + vg]) * 4;
    float k0_ = kbx[0], k1_ = kbx[1], k2_ = kbx[2], k3_ = kbx[3];
    float v0_ = vbx[0], v1_ = vbx[1], v2_ = vbx[2], v3_ = vbx[3];

    float kcx = (k0_ + k2_) * 0.5f, kcy = (k1_ + k3_) * 0.5f;
    float vcx = (v0_ + v2_) * 0.5f, vcy = (v1_ + v3_) * 0.5f;
    float dx = vcx - kcx, dy = vcy - kcy;
    float dist = sqrtf(dx * dx + dy * dy + EPSF);
    float angle = atan2f(dy, dx);
    float kh = k3_ - k1_, vh = v3_ - v1_, kw = k2_ - k0_, vw = v2_ - v0_;
    float h_ov = fmaxf(fminf(k3_, v3_) - fmaxf(k1_, v1_), 0.0f);
    float h_align = h_ov / (fminf(kh, vh) + EPSF);
    float v_ov = fmaxf(fminf(k2_, v2_) - fmaxf(k0_, v0_), 0.0f);
    float v_align = v_ov / (fminf(kw, vw) + EPSF);
    float area_ratio = (vh * vw) / (kh * kw + EPSF);
    float aspect = (vw / (vh + EPSF)) / (kw / (kh + EPSF));

    float4 sfa = {dx, dy, dist, angle};
    float4 sfb = {h_align, v_align, area_ratio, aspect};

    float4 h2v[8];
    #pragma unroll
    for (int q = 0; q < 8; ++q) h2v[q] = sbs2v[q];
    for (int j = 0; j < 64; ++j) {
        float4 w1a = sWs1T[j * 2], w1b = sWs1T[j * 2 + 1];
        float a = sbs1[j]
                + sfa.x * w1a.x + sfa.y * w1a.y + sfa.z * w1a.z + sfa.w * w1a.w
                + sfb.x * w1b.x + sfb.y * w1b.y + sfb.z * w1b.z + sfb.w * w1b.w;
        a = fmaxf(a, 0.0f);
        const float4* w2 = &sWs2v[j * 8];
        #pragma unroll
        for (int q = 0; q < 8; ++q) {
            float4 w = w2[q];
            h2v[q].x += a * w.x; h2v[q].y += a * w.y;
            h2v[q].z += a * w.z; h2v[q].w += a * w.w;
        }
    }
    float score = bf2[0];
    for (int tt = 0; tt < 16; ++tt) {
        float f = sbf1[tt] + c0 * sWf1c0[tt];
        const float4* w = &sWf1v[tt * 8];
        #pragma unroll
        for (int q = 0; q < 8; ++q) {
            float4 ww = w[q];
            f += h2v[q].x * ww.x + h2v[q].y * ww.y
               + h2v[q].z * ww.z + h2v[q].w * ww.w;
        }
        score += fmaxf(f, 0.0f) * sWf2[tt];
    }
    out[((size_t)b * KC + kg) * KC + vg] = score;
}

// ------------------------------------------------------------------
extern "C" void kernel_launch(void* const* d_in, const int* in_sizes, int n_in,
                              void* d_out, int out_size, void* d_ws, size_t ws_size,
                              hipStream_t stream) {
    const float* seq    = (const float*)d_in[0];
    const float* logits = (const float*)d_in[1];
    const float* bboxes = (const float*)d_in[2];
    const int*   mask   = (const int*)d_in[3];
    const float* Wk   = (const float*)d_in[4];
    const float* bk   = (const float*)d_in[5];
    const float* Wv   = (const float*)d_in[6];
    const float* bv   = (const float*)d_in[7];
    const float* Wbil = (const float*)d_in[8];
    const float* bbil = (const float*)d_in[9];
    const float* Ws1  = (const float*)d_in[10];
    const float* bs1  = (const float*)d_in[11];
    const float* Ws2  = (const float*)d_in[12];
    const float* bs2  = (const float*)d_in[13];
    const float* Wf1  = (const float*)d_in[14];
    const float* bf1  = (const float*)d_in[15];
    const float* Wf2  = (const float*)d_in[16];
    const float* bf2  = (const float*)d_in[17];

    float* out = (float*)d_out;
    char* ws = (char*)d_ws;

    // ws: idx @64 | Wt 6MB @8192 | Abf 2MB | reps 2MB (krep|vrep) | kbt 1MB
    int* key_idx = (int*)(ws + 64);
    int* val_idx = key_idx + B_ * KC;
    unsigned short* Wt   = (unsigned short*)(ws + 8192);
    unsigned short* Abf  = Wt + (size_t)3 * H_ * H_;
    unsigned short* reps = Abf + (size_t)1024 * H_;
    unsigned short* kbt  = reps + (size_t)1024 * H_;

    // L1: topk + weight transposes
    prep_kernel<<<3080, 256, 0, stream>>>(Wk, Wv, Wbil, Wt,
                                          logits, mask, key_idx, val_idx,
                                          out + B_ * KC * KC);
    // L2: gather + bf16 convert (once)
    gatherconv_kernel<<<1024, 256, 0, stream>>>(seq, key_idx, val_idx, Abf);
    // L3: krep (z=0) + vrep (z=1), LDS-staged GEMM
    gemm_lds_kernel<<<512, 256, 0, stream>>>(Abf, Wt, bk, bv, reps);
    // L4: kbt = krep @ WbilT
    gemm_lds_kernel<<<256, 256, 0, stream>>>(
        reps, Wt + (size_t)2 * H_ * H_, nullptr, nullptr, kbt);
    // L5: biaffine + spatial MLP
    biasp_kernel<<<256, 512, 0, stream>>>(kbt, reps + (size_t)512 * H_,
                                          bbil, bboxes, key_idx, val_idx,
                                          Ws1, bs1, Ws2, bs2,
                                          Wf1, bf1, Wf2, bf2, out);
}